// Round 2
// baseline (354.165 us; speedup 1.0000x reference)
//
#include <hip/hip_runtime.h>
#include <hip/hip_bf16.h>
#include <math.h>

#define NWRD 2000

typedef __attribute__((ext_vector_type(8)))  short short8;   // 8 bf16 (4 VGPRs)
typedef __attribute__((ext_vector_type(16))) float f32x16;   // MFMA 32x32 acc

// workspace layout (float offsets)
#define WS_FC2WT 0                         // 256*256 bf16
#define WS_WCODE (WS_FC2WT + 32768)        // 64*6000 f32  ([b][n*3+c])
#define WS_VSB   (WS_WCODE + 384000)       // (unused)
#define WS_W2T   (WS_VSB + 4096)           // vfb 256*256 bf16 (32768 f32-eq) + rbuf 256 f32
#define WS_VCB   (WS_W2T + 1536000)        // 64*128*256 bf16
#define WS_FCEWT (WS_VCB + 1048576)        // (unused)
#define WS_H0B   (WS_FCEWT + 4096)         // (unused)
#define WS_FCAWB (WS_H0B + 16384)          // 32*256 bf16 (row0=fca_w, rest 0)

__device__ __forceinline__ unsigned short f2bf(float x) {
    unsigned int u = __float_as_uint(x);
    u += 0x7fffu + ((u >> 16) & 1u);       // round-to-nearest-even
    return (unsigned short)(u >> 16);
}
// hardware packed f32->bf16 (RNE), 1 instr per 2 values
__device__ __forceinline__ unsigned int pkbf(float lo, float hi) {
    unsigned int r;
    asm("v_cvt_pk_bf16_f32 %0, %1, %2" : "=v"(r) : "v"(lo), "v"(hi));
    return r;
}

// ================ KPREP: prep jobs + fused wcode GEMM in ONE launch ================
// [0,94): wcode GEMM | [94,1118): vcb | [1118,1126): VF=vs@fce_w^T + rb | [1126,1142): fc2wT | 1142: fcawB
#define PR_K2  94
#define PR_VCB (PR_K2 + 1024)
#define PR_VF  (PR_VCB + 8)
#define PR_FC2 (PR_VF + 16)
#define PREP_N (PR_FC2 + 1)
__global__ __launch_bounds__(256) void kprep(
        const float* __restrict__ vc, unsigned short* __restrict__ vcb,
        const float* __restrict__ w2,
        const float* __restrict__ v, const float* __restrict__ w1,
        const float* __restrict__ b1, const float* __restrict__ b2,
        float* __restrict__ wcode,
        const float* __restrict__ vse_w1, const float* __restrict__ vse_b1,
        const float* __restrict__ vse_w2, const float* __restrict__ vse_b2,
        const float* __restrict__ fce_w, const float* __restrict__ fce_b,
        unsigned short* __restrict__ vfb, float* __restrict__ rbuf,
        const float* __restrict__ fc2_w, unsigned short* __restrict__ fc2wT,
        const float* __restrict__ fca_w, unsigned short* __restrict__ fcawB) {
    __shared__ __align__(16) unsigned short smem[10240];   // 20.5 KB unioned scratch
    int bid = blockIdx.x, t = threadIdx.x;
    if (bid < PR_K2) {
        // ---- wcode[64 b][64 n] = relu(v@w1+b1) @ w2[:,slice] + b2, via MFMA
        unsigned short* ha = smem;            // [64][72]
        unsigned short* wb = smem + 4608;     // [64][72]
        int n0 = bid * 64;
        int w = t >> 6, lane = t & 63, l31 = lane & 31, h = lane >> 5;
        int mt = w & 1, nt = w >> 1;
        int kk = t & 63, mg = t >> 6;
        int colc = n0 + kk; if (colc > 5999) colc = 5999;
        f32x16 acc;
#pragma unroll
        for (int i = 0; i < 16; i++) acc[i] = 0.f;
        for (int p = 0; p < 8; p++) {
            int k0 = p * 64;
            float w1c[7];
#pragma unroll
            for (int q = 0; q < 7; q++) w1c[q] = w1[q*512 + k0 + kk];
            float bbv = b1[k0 + kk];
#pragma unroll
            for (int mm = 0; mm < 16; mm++) {
                int m = mg*16 + mm;
                float s = bbv;
#pragma unroll
                for (int q = 0; q < 7; q++) s = fmaf(v[m*7 + q], w1c[q], s);
                ha[m*72 + kk] = f2bf(fmaxf(s, 0.f));
            }
#pragma unroll
            for (int i = 0; i < 16; i++)
                wb[kk*72 + mg*16 + i] = f2bf(w2[(size_t)(k0 + mg*16 + i)*6000 + colc]);
            __syncthreads();
#pragma unroll
            for (int ks = 0; ks < 4; ks++) {
                short8 af = *(const short8*)(ha + (mt*32 + l31)*72 + ks*16 + h*8);
                short8 bf = *(const short8*)(wb + (nt*32 + l31)*72 + ks*16 + h*8);
                acc = __builtin_amdgcn_mfma_f32_32x32x16_bf16(af, bf, acc, 0, 0, 0);
            }
            __syncthreads();
        }
        int n = n0 + nt*32 + l31;
        if (n < 6000) {
            float bias = b2[n];
#pragma unroll
            for (int i = 0; i < 16; i++) {
                int row = (i & 3) + 8*(i >> 2) + 4*h;
                wcode[(size_t)(mt*32 + row)*6000 + n] = acc[i] + bias;
            }
        }
    } else if (bid < PR_VCB) {
        // ---- view_cell f32 -> bf16
        int i = ((bid - PR_K2) * 256 + t) * 8;
        float4 f0 = *(const float4*)(vc + i);
        float4 f1 = *(const float4*)(vc + i + 4);
        union { short8 v8; unsigned int u[4]; } o;
        o.u[0] = pkbf(f0.x, f0.y); o.u[1] = pkbf(f0.z, f0.w);
        o.u[2] = pkbf(f1.x, f1.y); o.u[3] = pkbf(f1.z, f1.w);
        *(short8*)(vcb + i) = o.v8;
    } else if (bid < PR_VF) {
        // ---- VF[v][k] = sum_e vs[v,e]*fce_w[k,e]  (bf16, k-major); rb[v] = sum_e fce_b[e]*vs[v,e]
        float* hs  = (float*)smem;      // [32][128]
        float* vsf = hs + 4096;         // [32][32]
        int blk = bid - PR_VCB;
        int v0 = blk * 32;
#pragma unroll
        for (int q = 0; q < 16; q++) {
            int idx = q*256 + t;
            int vloc = idx >> 7, m = idx & 127;
            int vv = v0 + vloc;
            float x = (2.f/15.f)*(float)(vv >> 4) - 1.f;
            float y = (2.f/15.f)*(float)(vv & 15) - 1.f;
            hs[vloc*128 + m] = fmaxf(vse_b1[m] + x*vse_w1[m] + y*vse_w1[128 + m], 0.f);
        }
        __syncthreads();
#pragma unroll
        for (int q = 0; q < 4; q++) {
            int idx = q*256 + t;
            int vloc = idx >> 5, e = idx & 31;
            float s = vse_b2[e];
            for (int m = 0; m < 128; m++) s = fmaf(hs[vloc*128 + m], vse_w2[m*32 + e], s);
            vsf[vloc*32 + e] = s;
        }
        __syncthreads();
        {
            int vloc = t >> 3, kb = (t & 7) * 32;
            for (int j = 0; j < 32; j++) {
                int k = kb + j;
                float s = 0.f;
#pragma unroll
                for (int e = 0; e < 32; e++) s = fmaf(vsf[vloc*32 + e], fce_w[(size_t)k*32 + e], s);
                vfb[(size_t)(v0 + vloc)*256 + k] = f2bf(s);
            }
            if (t < 32) {
                float s = 0.f;
#pragma unroll
                for (int e = 0; e < 32; e++) s = fmaf(vsf[t*32 + e], fce_b[e], s);
                rbuf[v0 + t] = s;
            }
        }
    } else if (bid < PR_FC2) {
        // ---- fc2_w -> fc2wT (n-major bf16)
        unsigned short (*tile)[72] = (unsigned short(*)[72])smem;
        int b2t = bid - PR_VF;
        int k0t = (b2t >> 2) * 64, n0t = (b2t & 3) * 64;
        int nl = t & 63, kb = (t >> 6) * 16;
#pragma unroll
        for (int i = 0; i < 16; i++)
            tile[kb + i][nl] = f2bf(fc2_w[(size_t)(k0t + kb + i)*256 + n0t + nl]);
        __syncthreads();
        int kl = t & 63, nb = (t >> 6) * 16;
#pragma unroll
        for (int i = 0; i < 16; i++)
            fc2wT[(size_t)(n0t + nb + i)*256 + k0t + kl] = tile[kl][nb + i];
    } else {
        // ---- fcawB [32][256] bf16, row0 = fca_w, rest 0
        int e = t & 31, kb = (t >> 5) * 32;
#pragma unroll
        for (int i = 0; i < 32; i++)
            fcawB[(size_t)e*256 + kb + i] = (e == 0) ? f2bf(fca_w[kb + i]) : (unsigned short)0;
    }
}

// ================ K45: fused MLP + relation(VF) + softmax + einsum ================
// grid (16 nblk, 64 b), 512 threads (8 waves), 4 chunks of 32 words (128 words/block).
// LDS: h1b [32][264] @0 | h2b/routeB [32][264] @16896 | wcsAll[384] @33792 |
//      actP[2][32] @35328 | redS[8][32] @35584.  total 36608 B -> 4 blocks/CU.
#define K45_LDS 36608
__device__ __forceinline__ void fc1_row(const float* __restrict__ wr,
        const float4& wa, const float4& wb4, const float4& wc, const float4& bb4,
        unsigned short* dst) {
    float c0 = wr[0], c1 = wr[1], c2 = wr[2];
    float v0 = fmaxf(fmaf(c2, wc.x, fmaf(c1, wb4.x, fmaf(c0, wa.x, bb4.x))), 0.f);
    float v1 = fmaxf(fmaf(c2, wc.y, fmaf(c1, wb4.y, fmaf(c0, wa.y, bb4.y))), 0.f);
    float v2 = fmaxf(fmaf(c2, wc.z, fmaf(c1, wb4.z, fmaf(c0, wa.z, bb4.z))), 0.f);
    float v3 = fmaxf(fmaf(c2, wc.w, fmaf(c1, wb4.w, fmaf(c0, wa.w, bb4.w))), 0.f);
    uint2 p;
    p.x = pkbf(v0, v1);
    p.y = pkbf(v2, v3);
    *(uint2*)dst = p;
}
__global__ __launch_bounds__(512, 8) void k45(
        const unsigned short* __restrict__ vcb,
        const float* __restrict__ wcode,
        const float* __restrict__ fc1_w, const float* __restrict__ fc1_b,
        const unsigned short* __restrict__ fc2wT, const float* __restrict__ fc2_b,
        const float* __restrict__ fca_b_p,
        const unsigned short* __restrict__ fcawB,
        const unsigned short* __restrict__ vfb, const float* __restrict__ rbuf,
        float* __restrict__ out) {
    extern __shared__ char lds[];
    unsigned short* h1b    = (unsigned short*)lds;            // [32][264]
    unsigned short* h2b    = (unsigned short*)(lds + 16896);  // [32][264]
    unsigned short* routeB = h2b;                             // alias (h2 dead by write time)
    float* wcsAll = (float*)(lds + 33792);                    // [384]
    float* actP   = (float*)(lds + 35328);                    // [2][32] fca K-split partials
    float* redS   = (float*)(lds + 35584);                    // [8][32]
    int t = threadIdx.x;
    int w = t >> 6, lane = t & 63, l31 = lane & 31, h = lane >> 5;
    int b = blockIdx.y;
    int n0 = blockIdx.x * 128;

    // ---- stage this block's 128 words of wcode (384 f32)
    if (t < 384) {
        int i0 = n0*3 + t;
        wcsAll[t] = wcode[(size_t)b*6000 + (i0 < 6000 ? i0 : 5999)];
    }
    int nW = w*32 + l31;                       // fc2: wave owns one 32-feature tile
    float b2v = fc2_b[nW];
    float fcab = fca_b_p[0];
    size_t arowE = ((size_t)(b*128 + (w & 3)*32 + l31))*256;  // einsum A row (waves 0-3)
    __syncthreads();

    // ---- prologue: fc1(chunk 0) by all 8 waves
    {
        int jq = (t & 63) * 4;
        float4 wa  = *(const float4*)(fc1_w + jq);
        float4 wb4 = *(const float4*)(fc1_w + 256 + jq);
        float4 wc  = *(const float4*)(fc1_w + 512 + jq);
        float4 bb4 = *(const float4*)(fc1_b + jq);
        int rbase = (t >> 6) * 4;
#pragma unroll
        for (int rr = 0; rr < 4; rr++) {
            int r = rbase + rr;
            fc1_row(wcsAll + r*3, wa, wb4, wc, bb4, h1b + r*264 + jq);
        }
    }
    __syncthreads();   // B1: h1b(0) ready

    for (int c = 0; c < 4; c++) {
        // ---- fc2 (MFMA): [32 words] x [256 feats], wave owns 32 feats
        {
            f32x16 acc;
#pragma unroll
            for (int i = 0; i < 16; i++) acc[i] = 0.f;
#pragma unroll 4
            for (int ks = 0; ks < 16; ks++) {
                int k0 = ks*16 + h*8;
                short8 af = *(const short8*)(h1b + l31*264 + k0);
                short8 bf = *(const short8*)(fc2wT + (size_t)nW*256 + k0);
                acc = __builtin_amdgcn_mfma_f32_32x32x16_bf16(af, bf, acc, 0, 0, 0);
            }
#pragma unroll
            for (int i = 0; i < 16; i++) {
                int row = (i & 3) + 8*(i >> 2) + 4*h;
                h2b[row*264 + nW] = f2bf(fmaxf(acc[i] + b2v, 0.f));
            }
        }
        __syncthreads();   // B2: h2b ready
        // ---- fca partial (waves 6,7: K-split halves) -> actP
        if (w >= 6) {
            f32x16 ca;
#pragma unroll
            for (int i = 0; i < 16; i++) ca[i] = 0.f;
            int ksb = (w == 6) ? 0 : 8;
#pragma unroll
            for (int ks = 0; ks < 8; ks++) {
                int k0 = (ksb + ks)*16 + h*8;
                short8 af = *(const short8*)(fcawB + (size_t)l31*256 + k0);
                short8 bf = *(const short8*)(h2b + l31*264 + k0);
                ca = __builtin_amdgcn_mfma_f32_32x32x16_bf16(af, bf, ca, 0, 0, 0);
            }
            if (lane < 32) actP[(w - 6)*32 + l31] = ca[0];   // row0 = fca dim
        }
        // ---- relation (MFMA): D[v-rows (wave tile)][n-cols] = VF @ h2^T, K=256
        f32x16 ra;
#pragma unroll
        for (int i = 0; i < 16; i++) ra[i] = 0.f;
#pragma unroll 4
        for (int ks = 0; ks < 16; ks++) {
            int k0 = ks*16 + h*8;
            short8 af = *(const short8*)(vfb + (size_t)(w*32 + l31)*256 + k0);
            short8 bf = *(const short8*)(h2b + l31*264 + k0);
            ra = __builtin_amdgcn_mfma_f32_32x32x16_bf16(af, bf, ra, 0, 0, 0);
        }
        // ---- softmax partials (no max-sub: logits tiny; + rb bias from fce_b)
        float sm = 0.f;
#pragma unroll
        for (int i = 0; i < 16; i++) {
            int row = (i & 3) + 8*(i >> 2) + 4*h;
            float e = __expf(ra[i] + rbuf[w*32 + row]);
            ra[i] = e;
            sm += e;
        }
        sm += __shfl_xor(sm, 32);
        if (lane < 32) redS[w*32 + l31] = sm;
        __syncthreads();   // B4: redS, actP ready
        float smt = 0.f;
#pragma unroll
        for (int q = 0; q < 8; q++) smt += redS[q*32 + l31];
        float al = actP[l31] + actP[32 + l31] + fcab;
        float scale = (1.f / (1.f + __expf(-al))) / smt;
        // ---- routeB[n][v] bf16 (aliases h2b)
#pragma unroll
        for (int g = 0; g < 4; g++) {
            int vb = w*32 + 8*g + 4*h;
            unsigned int p0 = pkbf(ra[g*4+0]*scale, ra[g*4+1]*scale);
            unsigned int p1 = pkbf(ra[g*4+2]*scale, ra[g*4+3]*scale);
            *(uint2*)(routeB + l31*264 + vb) = make_uint2(p0, p1);
        }
        __syncthreads();   // B5: routeB ready
        // ---- einsum (waves 0-3)  ||  fc1(c+1) (waves 4-7)
        if (w < 4) {
            f32x16 cc;
#pragma unroll
            for (int i = 0; i < 16; i++) cc[i] = 0.f;
#pragma unroll 4
            for (int ks = 0; ks < 16; ks++) {
                int k0 = ks*16 + h*8;
                short8 bf = *(const short8*)(routeB + l31*264 + k0);
                short8 a0 = *(const short8*)(vcb + arowE + k0);
                cc = __builtin_amdgcn_mfma_f32_32x32x16_bf16(a0, bf, cc, 0, 0, 0);
            }
            int ng = n0 + c*32 + l31;
            if (ng < NWRD) {
                float* ob = out + (size_t)b*128*NWRD + ng;
#pragma unroll
                for (int i = 0; i < 16; i++) {
                    int crow = (i & 3) + 8*(i >> 2) + 4*h;
                    ob[(size_t)(w*32 + crow)*NWRD] = cc[i];
                }
            }
        } else if (c < 3) {
            int t2 = t & 255;
            int jq = (t2 & 63) * 4;
            float4 wa  = *(const float4*)(fc1_w + jq);
            float4 wb4 = *(const float4*)(fc1_w + 256 + jq);
            float4 wc  = *(const float4*)(fc1_w + 512 + jq);
            float4 bb4 = *(const float4*)(fc1_b + jq);
            int rbase = (t2 >> 6) * 8;
#pragma unroll
            for (int rr = 0; rr < 8; rr++) {
                int r = rbase + rr;
                fc1_row(wcsAll + ((c + 1)*32 + r)*3, wa, wb4, wc, bb4, h1b + r*264 + jq);
            }
        }
        if (c < 3) __syncthreads();   // B1: h1b(c+1) ready; routeB reads done
    }
}

extern "C" void kernel_launch(void* const* d_in, const int* in_sizes, int n_in,
                              void* d_out, int out_size, void* d_ws, size_t ws_size,
                              hipStream_t stream) {
    const float* view_cell = (const float*)d_in[0];
    const float* v       = (const float*)d_in[1];
    const float* w2c_w1  = (const float*)d_in[2];
    const float* w2c_b1  = (const float*)d_in[3];
    const float* w2c_w2  = (const float*)d_in[4];
    const float* w2c_b2  = (const float*)d_in[5];
    const float* fc1_w   = (const float*)d_in[6];
    const float* fc1_b   = (const float*)d_in[7];
    const float* fc2_w   = (const float*)d_in[8];
    const float* fc2_b   = (const float*)d_in[9];
    const float* fca_w   = (const float*)d_in[10];
    const float* fca_b   = (const float*)d_in[11];
    const float* fce_w   = (const float*)d_in[12];
    const float* fce_b   = (const float*)d_in[13];
    const float* vse_w1  = (const float*)d_in[14];
    const float* vse_b1  = (const float*)d_in[15];
    const float* vse_w2  = (const float*)d_in[16];
    const float* vse_b2  = (const float*)d_in[17];
    float* ws    = (float*)d_ws;
    unsigned short* fc2wT = (unsigned short*)(ws + WS_FC2WT);
    float* wcode = ws + WS_WCODE;
    unsigned short* vfb   = (unsigned short*)(ws + WS_W2T);
    float* rbuf  = ws + WS_W2T + 32768;
    unsigned short* vcb   = (unsigned short*)(ws + WS_VCB);
    unsigned short* fcawB = (unsigned short*)(ws + WS_FCAWB);
    float* out   = (float*)d_out;

    kprep<<<PREP_N, 256, 0, stream>>>(view_cell, vcb,
                                      w2c_w2, v, w2c_w1, w2c_b1, w2c_b2, wcode,
                                      vse_w1, vse_b1, vse_w2, vse_b2,
                                      fce_w, fce_b, vfb, rbuf,
                                      fc2_w, fc2wT, fca_w, fcawB);
    (void)hipFuncSetAttribute((const void*)k45,
                              hipFuncAttributeMaxDynamicSharedMemorySize, K45_LDS);
    dim3 g45(16, 64);
    k45<<<g45, 512, K45_LDS, stream>>>(vcb, wcode, fc1_w, fc1_b, fc2wT, fc2_b,
                                       fca_b, fcawB, vfb, rbuf, out);
}

// Round 3
// 255.728 us; speedup vs baseline: 1.3849x; 1.3849x over previous
//
#include <hip/hip_runtime.h>
#include <hip/hip_bf16.h>
#include <math.h>

#define NWRD 2000

typedef __attribute__((ext_vector_type(8)))  short short8;   // 8 bf16 (4 VGPRs)
typedef __attribute__((ext_vector_type(16))) float f32x16;   // MFMA 32x32 acc

// workspace layout (float offsets)
#define WS_FC2WT 0                         // 256*256 bf16
#define WS_WCODE (WS_FC2WT + 32768)        // 64*6000 f32  ([b][n*3+c])
#define WS_VSB   (WS_WCODE + 384000)       // (unused)
#define WS_W2T   (WS_VSB + 4096)           // vfb 256*256 bf16 (32768 f32-eq) + rbuf 256 f32
#define WS_VCB   (WS_W2T + 1536000)        // 64*128*256 bf16
#define WS_FCEWT (WS_VCB + 1048576)        // (unused)
#define WS_H0B   (WS_FCEWT + 4096)         // (unused)
#define WS_FCAWB (WS_H0B + 16384)          // 32*256 bf16 (row0=fca_w, rest 0)

__device__ __forceinline__ unsigned short f2bf(float x) {
    unsigned int u = __float_as_uint(x);
    u += 0x7fffu + ((u >> 16) & 1u);       // round-to-nearest-even
    return (unsigned short)(u >> 16);
}
// hardware packed f32->bf16 (RNE), 1 instr per 2 values
__device__ __forceinline__ unsigned int pkbf(float lo, float hi) {
    unsigned int r;
    asm("v_cvt_pk_bf16_f32 %0, %1, %2" : "=v"(r) : "v"(lo), "v"(hi));
    return r;
}

// ================ KPREP: prep jobs + fused wcode GEMM in ONE launch ================
// [0,94): wcode GEMM | [94,1118): vcb | [1118,1126): VF=vs@fce_w^T + rb | [1126,1142): fc2wT | 1142: fcawB
#define PR_K2  94
#define PR_VCB (PR_K2 + 1024)
#define PR_VF  (PR_VCB + 8)
#define PR_FC2 (PR_VF + 16)
#define PREP_N (PR_FC2 + 1)
__global__ __launch_bounds__(256) void kprep(
        const float* __restrict__ vc, unsigned short* __restrict__ vcb,
        const float* __restrict__ w2,
        const float* __restrict__ v, const float* __restrict__ w1,
        const float* __restrict__ b1, const float* __restrict__ b2,
        float* __restrict__ wcode,
        const float* __restrict__ vse_w1, const float* __restrict__ vse_b1,
        const float* __restrict__ vse_w2, const float* __restrict__ vse_b2,
        const float* __restrict__ fce_w, const float* __restrict__ fce_b,
        unsigned short* __restrict__ vfb, float* __restrict__ rbuf,
        const float* __restrict__ fc2_w, unsigned short* __restrict__ fc2wT,
        const float* __restrict__ fca_w, unsigned short* __restrict__ fcawB) {
    __shared__ __align__(16) unsigned short smem[10240];   // 20.5 KB unioned scratch
    int bid = blockIdx.x, t = threadIdx.x;
    if (bid < PR_K2) {
        // ---- wcode[64 b][64 n] = relu(v@w1+b1) @ w2[:,slice] + b2, via MFMA
        unsigned short* ha = smem;            // [64][72]
        unsigned short* wb = smem + 4608;     // [64][72]
        int n0 = bid * 64;
        int w = t >> 6, lane = t & 63, l31 = lane & 31, h = lane >> 5;
        int mt = w & 1, nt = w >> 1;
        int kk = t & 63, mg = t >> 6;
        int colc = n0 + kk; if (colc > 5999) colc = 5999;
        // hoist v into regs once: thread owns word-row m for h0 production
        float vr[7];
#pragma unroll
        for (int q = 0; q < 7; q++) vr[q] = v[kk*7 + q];
        f32x16 acc;
#pragma unroll
        for (int i = 0; i < 16; i++) acc[i] = 0.f;
        for (int p = 0; p < 8; p++) {
            int k0 = p * 64;
            // h0 panel: thread (m=kk, colgroup mg): 16 cols; w1 reads wave-uniform
#pragma unroll
            for (int i = 0; i < 16; i++) {
                int col = mg*16 + i;
                float s = b1[k0 + col];
#pragma unroll
                for (int q = 0; q < 7; q++) s = fmaf(vr[q], w1[q*512 + k0 + col], s);
                ha[kk*72 + col] = f2bf(fmaxf(s, 0.f));
            }
            // w2 panel transpose: coalesced f32 row reads -> bf16 n-major LDS
#pragma unroll
            for (int i = 0; i < 16; i++)
                wb[kk*72 + mg*16 + i] = f2bf(w2[(size_t)(k0 + mg*16 + i)*6000 + colc]);
            __syncthreads();
#pragma unroll
            for (int ks = 0; ks < 4; ks++) {
                short8 af = *(const short8*)(ha + (mt*32 + l31)*72 + ks*16 + h*8);
                short8 bf = *(const short8*)(wb + (nt*32 + l31)*72 + ks*16 + h*8);
                acc = __builtin_amdgcn_mfma_f32_32x32x16_bf16(af, bf, acc, 0, 0, 0);
            }
            __syncthreads();
        }
        int n = n0 + nt*32 + l31;
        if (n < 6000) {
            float bias = b2[n];
#pragma unroll
            for (int i = 0; i < 16; i++) {
                int row = (i & 3) + 8*(i >> 2) + 4*h;
                wcode[(size_t)(mt*32 + row)*6000 + n] = acc[i] + bias;
            }
        }
    } else if (bid < PR_VCB) {
        // ---- view_cell f32 -> bf16
        int i = ((bid - PR_K2) * 256 + t) * 8;
        float4 f0 = *(const float4*)(vc + i);
        float4 f1 = *(const float4*)(vc + i + 4);
        union { short8 v8; unsigned int u[4]; } o;
        o.u[0] = pkbf(f0.x, f0.y); o.u[1] = pkbf(f0.z, f0.w);
        o.u[2] = pkbf(f1.x, f1.y); o.u[3] = pkbf(f1.z, f1.w);
        *(short8*)(vcb + i) = o.v8;
    } else if (bid < PR_VF) {
        // ---- VF[v][k] = sum_e vs[v,e]*fce_w[k,e]  (bf16, k-major); rb[v] = sum_e fce_b[e]*vs[v,e]
        float* hs  = (float*)smem;      // [32][128]
        float* vsf = hs + 4096;         // [32][32]
        int blk = bid - PR_VCB;
        int v0 = blk * 32;
#pragma unroll
        for (int q = 0; q < 16; q++) {
            int idx = q*256 + t;
            int vloc = idx >> 7, m = idx & 127;
            int vv = v0 + vloc;
            float x = (2.f/15.f)*(float)(vv >> 4) - 1.f;
            float y = (2.f/15.f)*(float)(vv & 15) - 1.f;
            hs[vloc*128 + m] = fmaxf(vse_b1[m] + x*vse_w1[m] + y*vse_w1[128 + m], 0.f);
        }
        __syncthreads();
#pragma unroll
        for (int q = 0; q < 4; q++) {
            int idx = q*256 + t;
            int vloc = idx >> 5, e = idx & 31;
            float s = vse_b2[e];
            for (int m = 0; m < 128; m++) s = fmaf(hs[vloc*128 + m], vse_w2[m*32 + e], s);
            vsf[vloc*32 + e] = s;
        }
        __syncthreads();
        {
            int vloc = t >> 3, kb = (t & 7) * 32;
            for (int j = 0; j < 32; j++) {
                int k = kb + j;
                float s = 0.f;
#pragma unroll
                for (int e = 0; e < 32; e++) s = fmaf(vsf[vloc*32 + e], fce_w[(size_t)k*32 + e], s);
                vfb[(size_t)(v0 + vloc)*256 + k] = f2bf(s);
            }
            if (t < 32) {
                float s = 0.f;
#pragma unroll
                for (int e = 0; e < 32; e++) s = fmaf(vsf[t*32 + e], fce_b[e], s);
                rbuf[v0 + t] = s;
            }
        }
    } else if (bid < PR_FC2) {
        // ---- fc2_w -> fc2wT (n-major bf16)
        unsigned short (*tile)[72] = (unsigned short(*)[72])smem;
        int b2t = bid - PR_VF;
        int k0t = (b2t >> 2) * 64, n0t = (b2t & 3) * 64;
        int nl = t & 63, kb = (t >> 6) * 16;
#pragma unroll
        for (int i = 0; i < 16; i++)
            tile[kb + i][nl] = f2bf(fc2_w[(size_t)(k0t + kb + i)*256 + n0t + nl]);
        __syncthreads();
        int kl = t & 63, nb = (t >> 6) * 16;
#pragma unroll
        for (int i = 0; i < 16; i++)
            fc2wT[(size_t)(n0t + nb + i)*256 + k0t + kl] = tile[kl][nb + i];
    } else {
        // ---- fcawB [32][256] bf16, row0 = fca_w, rest 0
        int e = t & 31, kb = (t >> 5) * 32;
#pragma unroll
        for (int i = 0; i < 32; i++)
            fcawB[(size_t)e*256 + kb + i] = (e == 0) ? f2bf(fca_w[kb + i]) : (unsigned short)0;
    }
}

// ================ K45: fused MLP + relation(VF) + deferred-softmax einsum ================
// grid (8 nblk, 64 b), 512 threads (8 waves), 4 chunks of 64 words.
// Ping-pong: h1(c) in buf[c&1]; h2(c) in buf[1-(c&1)]; unnormalized exp-route(c)
// overwrites h1(c)'s slot (dead after fc2). Normalization (act/sm) applied in the
// einsum epilogue -> no route-pack phase, 3 barriers/chunk.
// LDS: bufA @0 [64][264] | bufB @33792 | wcs[768] @67584 | redS[8][64] @70656 |
//      actP[64] @72704.  total 72960 -> pad 73216. 2 blocks/CU.
#define K45_LDS 73216
__device__ __forceinline__ void fc1_row(const float* __restrict__ wr,
        const float4& wa, const float4& wb4, const float4& wc, const float4& bb4,
        unsigned short* dst) {
    float c0 = wr[0], c1 = wr[1], c2 = wr[2];
    float v0 = fmaxf(fmaf(c2, wc.x, fmaf(c1, wb4.x, fmaf(c0, wa.x, bb4.x))), 0.f);
    float v1 = fmaxf(fmaf(c2, wc.y, fmaf(c1, wb4.y, fmaf(c0, wa.y, bb4.y))), 0.f);
    float v2 = fmaxf(fmaf(c2, wc.z, fmaf(c1, wb4.z, fmaf(c0, wa.z, bb4.z))), 0.f);
    float v3 = fmaxf(fmaf(c2, wc.w, fmaf(c1, wb4.w, fmaf(c0, wa.w, bb4.w))), 0.f);
    uint2 p;
    p.x = pkbf(v0, v1);
    p.y = pkbf(v2, v3);
    *(uint2*)dst = p;
}
__global__ __launch_bounds__(512, 4) void k45(
        const unsigned short* __restrict__ vcb,
        const float* __restrict__ wcode,
        const float* __restrict__ fc1_w, const float* __restrict__ fc1_b,
        const unsigned short* __restrict__ fc2wT, const float* __restrict__ fc2_b,
        const float* __restrict__ fca_b_p,
        const unsigned short* __restrict__ fcawB,
        const unsigned short* __restrict__ vfb, const float* __restrict__ rbuf,
        float* __restrict__ out) {
    extern __shared__ char lds[];
    unsigned short* bufA  = (unsigned short*)lds;             // [64][264]
    unsigned short* bufB  = (unsigned short*)(lds + 33792);   // [64][264]
    float* wcsAll = (float*)(lds + 67584);                    // [768]
    float* redS   = (float*)(lds + 70656);                    // [8][64]
    float* actP   = (float*)(lds + 72704);                    // [64] raw fca logits
    int t = threadIdx.x;
    int w = t >> 6, lane = t & 63, l31 = lane & 31, h = lane >> 5;
    int b = blockIdx.y;
    int n0 = blockIdx.x * 256;

    // ---- stage all 4 chunks' wcode once (768 f32)
    {
        const float* wsrc = wcode + (size_t)b*6000;
        int i0 = n0*3 + t;
        wcsAll[t] = wsrc[i0 < 6000 ? i0 : 5999];
        if (t < 256) {
            int i1 = n0*3 + 512 + t;
            wcsAll[512 + t] = wsrc[i1 < 6000 ? i1 : 5999];
        }
    }
    // hoisted invariants
    int jq = (t & 63) * 4;
    float4 wa  = *(const float4*)(fc1_w + jq);
    float4 wb4 = *(const float4*)(fc1_w + 256 + jq);
    float4 wc  = *(const float4*)(fc1_w + 512 + jq);
    float4 bb4 = *(const float4*)(fc1_b + jq);
    int nW = w*32 + l31;                       // fc2: wave owns one 32-feature tile
    float b2v = fc2_b[nW];
    float fcab = fca_b_p[0];
    int cq = w >> 1, ntE = w & 1;              // einsum tiling: 4 c-tiles x 2 n-tiles
    size_t arowE = ((size_t)(b*128 + cq*32 + l31))*256;
    float rbv[16];                             // rb bias per relation acc element
#pragma unroll
    for (int i = 0; i < 16; i++)
        rbv[i] = rbuf[w*32 + (i & 3) + 8*(i >> 2) + 4*h];
    __syncthreads();

    // ---- prologue: fc1(chunk 0) -> bufA
#pragma unroll
    for (int rr = 0; rr < 8; rr++) {
        int r = w*8 + rr;
        fc1_row(wcsAll + r*3, wa, wb4, wc, bb4, bufA + r*264 + jq);
    }
    __syncthreads();   // B1: h1(0) ready

    for (int c = 0; c < 4; c++) {
        unsigned short* hS = (c & 1) ? bufB : bufA;   // h1(c), later route(c)
        unsigned short* oS = (c & 1) ? bufA : bufB;   // h2(c), later h1(c+1)
        // ---- fc2 (MFMA): wave owns 32-feature tile, both 32-word halves; B loaded once
        {
            f32x16 c0, c1;
#pragma unroll
            for (int i = 0; i < 16; i++) { c0[i] = 0.f; c1[i] = 0.f; }
#pragma unroll 4
            for (int ks = 0; ks < 16; ks++) {
                int k0 = ks*16 + h*8;
                short8 bf  = *(const short8*)(fc2wT + (size_t)nW*256 + k0);
                short8 af0 = *(const short8*)(hS + l31*264 + k0);
                short8 af1 = *(const short8*)(hS + (32 + l31)*264 + k0);
                c0 = __builtin_amdgcn_mfma_f32_32x32x16_bf16(af0, bf, c0, 0, 0, 0);
                c1 = __builtin_amdgcn_mfma_f32_32x32x16_bf16(af1, bf, c1, 0, 0, 0);
            }
#pragma unroll
            for (int i = 0; i < 16; i++) {
                int row = (i & 3) + 8*(i >> 2) + 4*h;
                unsigned int pk = pkbf(fmaxf(c0[i] + b2v, 0.f), fmaxf(c1[i] + b2v, 0.f));
                oS[row*264 + nW]        = (unsigned short)pk;
                oS[(row + 32)*264 + nW] = (unsigned short)(pk >> 16);
            }
        }
        __syncthreads();   // B2: h2 ready
        // ---- fca raw logits (waves 6,7: one 32-word half each, full K) -> actP
        if (w >= 6) {
            f32x16 ca;
#pragma unroll
            for (int i = 0; i < 16; i++) ca[i] = 0.f;
            int wh = (w - 6) * 32;
#pragma unroll 4
            for (int ks = 0; ks < 16; ks++) {
                int k0 = ks*16 + h*8;
                short8 af = *(const short8*)(fcawB + (size_t)l31*256 + k0);
                short8 bf = *(const short8*)(oS + (wh + l31)*264 + k0);
                ca = __builtin_amdgcn_mfma_f32_32x32x16_bf16(af, bf, ca, 0, 0, 0);
            }
            if (lane < 32) actP[wh + l31] = ca[0];   // row0 = fca dim
        }
        // ---- relation (MFMA, all 8 waves): D[v-tile w][64 word-cols], K=256
        f32x16 ra0, ra1;
#pragma unroll
        for (int i = 0; i < 16; i++) { ra0[i] = 0.f; ra1[i] = 0.f; }
#pragma unroll 4
        for (int ks = 0; ks < 16; ks++) {
            int k0 = ks*16 + h*8;
            short8 af  = *(const short8*)(vfb + (size_t)(w*32 + l31)*256 + k0);
            short8 bf0 = *(const short8*)(oS + l31*264 + k0);
            short8 bf1 = *(const short8*)(oS + (32 + l31)*264 + k0);
            ra0 = __builtin_amdgcn_mfma_f32_32x32x16_bf16(af, bf0, ra0, 0, 0, 0);
            ra1 = __builtin_amdgcn_mfma_f32_32x32x16_bf16(af, bf1, ra1, 0, 0, 0);
        }
        // ---- exp (no max-sub: logits tiny) + per-wave column sums
        float sm0 = 0.f, sm1 = 0.f;
#pragma unroll
        for (int i = 0; i < 16; i++) {
            float e0 = __expf(ra0[i] + rbv[i]);
            float e1 = __expf(ra1[i] + rbv[i]);
            ra0[i] = e0; ra1[i] = e1;
            sm0 += e0; sm1 += e1;
        }
        sm0 += __shfl_xor(sm0, 32);
        sm1 += __shfl_xor(sm1, 32);
        if (lane < 32) {
            redS[w*64 + l31]      = sm0;
            redS[w*64 + 32 + l31] = sm1;
        }
        // ---- pack UNNORMALIZED exp route into hS (h1 dead after fc2)
#pragma unroll
        for (int g = 0; g < 4; g++) {
            int vb = w*32 + 8*g + 4*h;
            unsigned int p0 = pkbf(ra0[g*4+0], ra0[g*4+1]);
            unsigned int p1 = pkbf(ra0[g*4+2], ra0[g*4+3]);
            *(uint2*)(hS + l31*264 + vb) = make_uint2(p0, p1);
            unsigned int q0 = pkbf(ra1[g*4+0], ra1[g*4+1]);
            unsigned int q1 = pkbf(ra1[g*4+2], ra1[g*4+3]);
            *(uint2*)(hS + (32 + l31)*264 + vb) = make_uint2(q0, q1);
        }
        __syncthreads();   // B4: route, redS, actP ready
        // ---- einsum (all 8 waves): out = (vcb @ e^T) * (act/sm) per word-col
        {
            f32x16 cc;
#pragma unroll
            for (int i = 0; i < 16; i++) cc[i] = 0.f;
            const unsigned short* rrow = hS + (ntE*32 + l31)*264;
#pragma unroll 4
            for (int ks = 0; ks < 16; ks++) {
                int k0 = ks*16 + h*8;
                short8 bf = *(const short8*)(rrow + k0);
                short8 a0 = *(const short8*)(vcb + arowE + k0);
                cc = __builtin_amdgcn_mfma_f32_32x32x16_bf16(a0, bf, cc, 0, 0, 0);
            }
            int wloc = ntE*32 + l31;
            float smt = 0.f;
#pragma unroll
            for (int q = 0; q < 8; q++) smt += redS[q*64 + wloc];
            float al = actP[wloc] + fcab;
            float scale = (1.f / (1.f + __expf(-al))) / smt;
            int ng = n0 + c*64 + wloc;
            if (ng < NWRD) {
                float* ob = out + (size_t)b*128*NWRD + ng;
#pragma unroll
                for (int i = 0; i < 16; i++) {
                    int crow = (i & 3) + 8*(i >> 2) + 4*h;
                    __builtin_nontemporal_store(cc[i]*scale,
                                                ob + (size_t)(cq*32 + crow)*NWRD);
                }
            }
        }
        // ---- fc1(c+1) -> oS (h2 dead after rel/fca), overlaps einsum in-stream
        if (c < 3) {
#pragma unroll
            for (int rr = 0; rr < 8; rr++) {
                int r = w*8 + rr;
                fc1_row(wcsAll + ((c + 1)*64 + r)*3, wa, wb4, wc, bb4, oS + r*264 + jq);
            }
            __syncthreads();   // B1: h1(c+1) ready; route(c) reads done
        }
    }
}

extern "C" void kernel_launch(void* const* d_in, const int* in_sizes, int n_in,
                              void* d_out, int out_size, void* d_ws, size_t ws_size,
                              hipStream_t stream) {
    const float* view_cell = (const float*)d_in[0];
    const float* v       = (const float*)d_in[1];
    const float* w2c_w1  = (const float*)d_in[2];
    const float* w2c_b1  = (const float*)d_in[3];
    const float* w2c_w2  = (const float*)d_in[4];
    const float* w2c_b2  = (const float*)d_in[5];
    const float* fc1_w   = (const float*)d_in[6];
    const float* fc1_b   = (const float*)d_in[7];
    const float* fc2_w   = (const float*)d_in[8];
    const float* fc2_b   = (const float*)d_in[9];
    const float* fca_w   = (const float*)d_in[10];
    const float* fca_b   = (const float*)d_in[11];
    const float* fce_w   = (const float*)d_in[12];
    const float* fce_b   = (const float*)d_in[13];
    const float* vse_w1  = (const float*)d_in[14];
    const float* vse_b1  = (const float*)d_in[15];
    const float* vse_w2  = (const float*)d_in[16];
    const float* vse_b2  = (const float*)d_in[17];
    float* ws    = (float*)d_ws;
    unsigned short* fc2wT = (unsigned short*)(ws + WS_FC2WT);
    float* wcode = ws + WS_WCODE;
    unsigned short* vfb   = (unsigned short*)(ws + WS_W2T);
    float* rbuf  = ws + WS_W2T + 32768;
    unsigned short* vcb   = (unsigned short*)(ws + WS_VCB);
    unsigned short* fcawB = (unsigned short*)(ws + WS_FCAWB);
    float* out   = (float*)d_out;

    kprep<<<PREP_N, 256, 0, stream>>>(view_cell, vcb,
                                      w2c_w2, v, w2c_w1, w2c_b1, w2c_b2, wcode,
                                      vse_w1, vse_b1, vse_w2, vse_b2,
                                      fce_w, fce_b, vfb, rbuf,
                                      fc2_w, fc2wT, fca_w, fcawB);
    (void)hipFuncSetAttribute((const void*)k45,
                              hipFuncAttributeMaxDynamicSharedMemorySize, K45_LDS);
    dim3 g45(8, 64);
    k45<<<g45, 512, K45_LDS, stream>>>(vcb, wcode, fc1_w, fc1_b, fc2wT, fc2_b,
                                       fca_b, fcawB, vfb, rbuf, out);
}

// Round 4
// 251.217 us; speedup vs baseline: 1.4098x; 1.0180x over previous
//
#include <hip/hip_runtime.h>
#include <hip/hip_bf16.h>
#include <math.h>

#define NWRD 2000

typedef __attribute__((ext_vector_type(8)))  short short8;   // 8 bf16 (4 VGPRs)
typedef __attribute__((ext_vector_type(16))) float f32x16;   // MFMA 32x32 acc

// workspace layout (float offsets)
#define WS_FC2WT 0                         // 256*256 bf16
#define WS_WCODE (WS_FC2WT + 32768)        // 64*6000 f32  ([b][n*3+c])
#define WS_VSB   (WS_WCODE + 384000)       // 256*32 bf16
#define WS_W2T   (WS_VSB + 4096)           // (unused)
#define WS_VCB   (WS_W2T + 1536000)        // 64*128*256 bf16
#define WS_FCEWT (WS_VCB + 1048576)        // 32*256 bf16
#define WS_H0B   (WS_FCEWT + 4096)         // (unused)
#define WS_FCAWB (WS_H0B + 16384)          // 32*256 bf16 (row0=fca_w, rest 0)

__device__ __forceinline__ unsigned short f2bf(float x) {
    unsigned int u = __float_as_uint(x);
    u += 0x7fffu + ((u >> 16) & 1u);       // round-to-nearest-even
    return (unsigned short)(u >> 16);
}
// hardware packed f32->bf16 (RNE), 1 instr per 2 values
__device__ __forceinline__ unsigned int pkbf(float lo, float hi) {
    unsigned int r;
    asm("v_cvt_pk_bf16_f32 %0, %1, %2" : "=v"(r) : "v"(lo), "v"(hi));
    return r;
}

// ================ KPREP: prep jobs + fused wcode GEMM in ONE launch ================
// [0,94): wcode GEMM | [94,1118): vcb | [1118,1150): vsb | [1150,1166): fc2wT | 1166: fcewT+fcawB
#define PR_K2  94
#define PR_VCB (PR_K2 + 1024)
#define PR_VSB (PR_VCB + 32)
#define PR_FC2 (PR_VSB + 16)
#define PREP_N (PR_FC2 + 1)
__global__ __launch_bounds__(256) void kprep(
        const float* __restrict__ vc, unsigned short* __restrict__ vcb,
        const float* __restrict__ w2,
        const float* __restrict__ v, const float* __restrict__ w1,
        const float* __restrict__ b1, const float* __restrict__ b2,
        float* __restrict__ wcode,
        const float* __restrict__ vse_w1, const float* __restrict__ vse_b1,
        const float* __restrict__ vse_w2, const float* __restrict__ vse_b2,
        unsigned short* __restrict__ vsb,
        const float* __restrict__ fc2_w, unsigned short* __restrict__ fc2wT,
        const float* __restrict__ fce_w, unsigned short* __restrict__ fcewT,
        const float* __restrict__ fca_w, unsigned short* __restrict__ fcawB) {
    __shared__ __align__(16) unsigned short smem[10240];   // 20.5 KB unioned scratch
    int bid = blockIdx.x, t = threadIdx.x;
    if (bid < PR_K2) {
        // ---- wcode[64 b][64 n] = relu(v@w1+b1) @ w2[:,slice] + b2, via MFMA
        unsigned short* ha = smem;            // [64][72]
        unsigned short* wb = smem + 4608;     // [64][72]
        int n0 = bid * 64;
        int w = t >> 6, lane = t & 63, l31 = lane & 31, h = lane >> 5;
        int mt = w & 1, nt = w >> 1;
        int kk = t & 63, mg = t >> 6;
        int colc = n0 + kk; if (colc > 5999) colc = 5999;
        f32x16 acc;
#pragma unroll
        for (int i = 0; i < 16; i++) acc[i] = 0.f;
        for (int p = 0; p < 8; p++) {
            int k0 = p * 64;
            // h0 panel: thread owns column kk, 16 rows (m = b index); w1 reads coalesced
            float w1c[7];
#pragma unroll
            for (int q = 0; q < 7; q++) w1c[q] = w1[q*512 + k0 + kk];
            float bbv = b1[k0 + kk];
#pragma unroll
            for (int mm = 0; mm < 16; mm++) {
                int m = mg*16 + mm;           // wave-uniform m -> scalar v loads
                float s = bbv;
#pragma unroll
                for (int q = 0; q < 7; q++) s = fmaf(v[m*7 + q], w1c[q], s);
                ha[m*72 + kk] = f2bf(fmaxf(s, 0.f));
            }
            // w2 panel transpose: coalesced f32 row reads -> bf16 n-major LDS
#pragma unroll
            for (int i = 0; i < 16; i++)
                wb[kk*72 + mg*16 + i] = f2bf(w2[(size_t)(k0 + mg*16 + i)*6000 + colc]);
            __syncthreads();
#pragma unroll
            for (int ks = 0; ks < 4; ks++) {
                short8 af = *(const short8*)(ha + (mt*32 + l31)*72 + ks*16 + h*8);
                short8 bf = *(const short8*)(wb + (nt*32 + l31)*72 + ks*16 + h*8);
                acc = __builtin_amdgcn_mfma_f32_32x32x16_bf16(af, bf, acc, 0, 0, 0);
            }
            __syncthreads();
        }
        int n = n0 + nt*32 + l31;
        if (n < 6000) {
            float bias = b2[n];
#pragma unroll
            for (int i = 0; i < 16; i++) {
                int row = (i & 3) + 8*(i >> 2) + 4*h;
                wcode[(size_t)(mt*32 + row)*6000 + n] = acc[i] + bias;
            }
        }
    } else if (bid < PR_VCB) {
        // ---- view_cell f32 -> bf16
        int i = ((bid - PR_K2) * 256 + t) * 8;
        float4 f0 = *(const float4*)(vc + i);
        float4 f1 = *(const float4*)(vc + i + 4);
        union { short8 v8; unsigned int u[4]; } o;
        o.u[0] = pkbf(f0.x, f0.y); o.u[1] = pkbf(f0.z, f0.w);
        o.u[2] = pkbf(f1.x, f1.y); o.u[3] = pkbf(f1.z, f1.w);
        *(short8*)(vcb + i) = o.v8;
    } else if (bid < PR_VSB) {
        // ---- vs MLP -> bf16
        float* hs = (float*)smem;   // [8][128]
        int blk = bid - PR_VCB;
        int m = t & 127, half = t >> 7;
#pragma unroll
        for (int q = 0; q < 4; q++) {
            int vloc = half*4 + q;
            int vv = blk*8 + vloc;
            float x = (2.f/15.f)*(float)(vv >> 4) - 1.f;
            float y = (2.f/15.f)*(float)(vv & 15) - 1.f;
            float hh = vse_b1[m] + x*vse_w1[m] + y*vse_w1[128 + m];
            hs[vloc*128 + m] = fmaxf(hh, 0.f);
        }
        __syncthreads();
        int vloc = t >> 5, e = t & 31;
        float s = vse_b2[e];
        for (int mm = 0; mm < 128; mm++) s = fmaf(hs[vloc*128 + mm], vse_w2[mm*32 + e], s);
        vsb[(blk*8 + vloc)*32 + e] = f2bf(s);
    } else if (bid < PR_FC2) {
        // ---- fc2_w -> fc2wT (n-major bf16)
        unsigned short (*tile)[72] = (unsigned short(*)[72])smem;
        int b2t = bid - PR_VSB;
        int k0t = (b2t >> 2) * 64, n0t = (b2t & 3) * 64;
        int nl = t & 63, kb = (t >> 6) * 16;
#pragma unroll
        for (int i = 0; i < 16; i++)
            tile[kb + i][nl] = f2bf(fc2_w[(size_t)(k0t + kb + i)*256 + n0t + nl]);
        __syncthreads();
        int kl = t & 63, nb = (t >> 6) * 16;
#pragma unroll
        for (int i = 0; i < 16; i++)
            fc2wT[(size_t)(n0t + nb + i)*256 + k0t + kl] = tile[kl][nb + i];
    } else {
        // ---- fcewT (32x256 bf16, e-major) + fcawB (row0 = fca_w, rest 0)
        int e = t & 31, kb = (t >> 5) * 32;
        unsigned short tmp[32];
#pragma unroll
        for (int i = 0; i < 32; i++) tmp[i] = f2bf(fce_w[(size_t)(kb + i)*32 + e]);
#pragma unroll
        for (int i = 0; i < 4; i++)
            *(short8*)(fcewT + (size_t)e*256 + kb + i*8) = *(short8*)(tmp + i*8);
#pragma unroll
        for (int i = 0; i < 32; i++)
            fcawB[(size_t)e*256 + kb + i] = (e == 0) ? f2bf(fca_w[kb + i]) : (unsigned short)0;
    }
}

// ================ K45: single-buffer in-place pipeline, 3 blocks/CU ================
// grid (8 nblk, 64 b), 512 threads (8 waves), 4 chunks of 64 words.
// ONE [64][264] bf16 buffer holds h1 -> (in-place) h2 -> (in-place) exp-route.
// fc2 reads h1 fully into accumulators, barrier, writes h2 over it.
// Deferred softmax: route stores raw exp; act/sum applied in einsum epilogue.
// LDS: buf @0 (33792) | embL [64][40] @33792 | wcs[768] @38912 | redS[8][32] @41984 |
//      actL[64] @43008. total 43264 B -> 3 blocks/CU (24 waves).
#define K45_LDS 43264
__device__ __forceinline__ void fc1_row(const float* __restrict__ wr,
        const float4& wa, const float4& wb4, const float4& wc, const float4& bb4,
        unsigned short* dst) {
    float c0 = wr[0], c1 = wr[1], c2 = wr[2];
    float v0 = fmaxf(fmaf(c2, wc.x, fmaf(c1, wb4.x, fmaf(c0, wa.x, bb4.x))), 0.f);
    float v1 = fmaxf(fmaf(c2, wc.y, fmaf(c1, wb4.y, fmaf(c0, wa.y, bb4.y))), 0.f);
    float v2 = fmaxf(fmaf(c2, wc.z, fmaf(c1, wb4.z, fmaf(c0, wa.z, bb4.z))), 0.f);
    float v3 = fmaxf(fmaf(c2, wc.w, fmaf(c1, wb4.w, fmaf(c0, wa.w, bb4.w))), 0.f);
    uint2 p;
    p.x = pkbf(v0, v1);
    p.y = pkbf(v2, v3);
    *(uint2*)dst = p;
}
__global__ __launch_bounds__(512, 6) void k45(
        const unsigned short* __restrict__ vcb,
        const float* __restrict__ wcode,
        const float* __restrict__ fc1_w, const float* __restrict__ fc1_b,
        const unsigned short* __restrict__ fc2wT, const float* __restrict__ fc2_b,
        const float* __restrict__ fca_b_p,
        const unsigned short* __restrict__ fcawB,
        const unsigned short* __restrict__ fcewT, const float* __restrict__ fce_b,
        const unsigned short* __restrict__ vsb,
        float* __restrict__ out) {
    extern __shared__ char lds[];
    unsigned short* buf   = (unsigned short*)lds;             // [64][264]
    unsigned short* embL  = (unsigned short*)(lds + 33792);   // [64][40]
    float* wcsAll = (float*)(lds + 38912);                    // [768]
    float* redS   = (float*)(lds + 41984);                    // [8][32]
    float* actL   = (float*)(lds + 43008);                    // [64] raw fca logits
    int t = threadIdx.x;
    int w = t >> 6, lane = t & 63, l31 = lane & 31, h = lane >> 5;
    int b = blockIdx.y;
    int n0 = blockIdx.x * 256;

    // ---- stage all 4 chunks' wcode once (768 f32)
    {
        const float* wsrc = wcode + (size_t)b*6000;
        int i0 = n0*3 + t;
        wcsAll[t] = wsrc[i0 < 6000 ? i0 : 5999];
        if (t < 256) {
            int i1 = n0*3 + 512 + t;
            wcsAll[512 + t] = wsrc[i1 < 6000 ? i1 : 5999];
        }
    }
    // hoisted invariants (small live set; fc1 weights reloaded per chunk)
    int jq = (t & 63) * 4;
    int mtF = w & 1, nqF = w >> 1;             // fc2: wave = (m-half, n-quarter)
    int colA = nqF*64 + l31, colB = colA + 32;
    float baA = fc2_b[colA], baB = fc2_b[colB];
    float be = fce_b[l31];
    float fcab = fca_b_p[0];
    int ntR = w & 1, vq = w >> 1;              // relation tiling
    int cq = w >> 1, ntE = w & 1;              // einsum tiling
    size_t arowE = ((size_t)(b*128 + cq*32 + l31))*256;
    __syncthreads();

    for (int c = 0; c < 4; c++) {
        // ---- P0: fc1 -> buf (h1)
        {
            float4 wa  = *(const float4*)(fc1_w + jq);
            float4 wb4 = *(const float4*)(fc1_w + 256 + jq);
            float4 wc  = *(const float4*)(fc1_w + 512 + jq);
            float4 bb4 = *(const float4*)(fc1_b + jq);
#pragma unroll
            for (int rr = 0; rr < 8; rr++) {
                int r = w*8 + rr;
                fc1_row(wcsAll + (c*64 + r)*3, wa, wb4, wc, bb4, buf + r*264 + jq);
            }
        }
        __syncthreads();   // A: h1 ready
        // ---- P1: fc2 MFMA (read-only; wave reads only its m-half of A)
        f32x16 c0, c1;
#pragma unroll
        for (int i = 0; i < 16; i++) { c0[i] = 0.f; c1[i] = 0.f; }
#pragma unroll 4
        for (int ks = 0; ks < 16; ks++) {
            int k0 = ks*16 + h*8;
            short8 af  = *(const short8*)(buf + (mtF*32 + l31)*264 + k0);
            short8 bf0 = *(const short8*)(fc2wT + (size_t)colA*256 + k0);
            short8 bf1 = *(const short8*)(fc2wT + (size_t)colB*256 + k0);
            c0 = __builtin_amdgcn_mfma_f32_32x32x16_bf16(af, bf0, c0, 0, 0, 0);
            c1 = __builtin_amdgcn_mfma_f32_32x32x16_bf16(af, bf1, c1, 0, 0, 0);
        }
        __syncthreads();   // B: all h1 reads done
        // ---- P2: write h2 in place
#pragma unroll
        for (int i = 0; i < 16; i++) {
            int row = (i & 3) + 8*(i >> 2) + 4*h;
            unsigned int pk = pkbf(fmaxf(c0[i] + baA, 0.f), fmaxf(c1[i] + baB, 0.f));
            buf[(mtF*32 + row)*264 + colA] = (unsigned short)pk;
            buf[(mtF*32 + row)*264 + colB] = (unsigned short)(pk >> 16);
        }
        __syncthreads();   // C: h2 ready
        // ---- P3: fce (waves 0-1) + fca (waves 2-3) read h2
        if (w < 2) {
            f32x16 ce;
#pragma unroll
            for (int i = 0; i < 16; i++) ce[i] = 0.f;
#pragma unroll 4
            for (int ks = 0; ks < 16; ks++) {
                int k0 = ks*16 + h*8;
                short8 af = *(const short8*)(buf + (w*32 + l31)*264 + k0);
                short8 bf = *(const short8*)(fcewT + (size_t)l31*256 + k0);
                ce = __builtin_amdgcn_mfma_f32_32x32x16_bf16(af, bf, ce, 0, 0, 0);
            }
#pragma unroll
            for (int i = 0; i < 16; i += 2) {
                int row = (i & 3) + 8*(i >> 2) + 4*h;
                unsigned int pk = pkbf(ce[i] + be, ce[i+1] + be);
                embL[(w*32 + row)*40 + l31]     = (unsigned short)pk;
                embL[(w*32 + row + 1)*40 + l31] = (unsigned short)(pk >> 16);
            }
        } else if (w < 4) {
            int m = w - 2;
            f32x16 ca;
#pragma unroll
            for (int i = 0; i < 16; i++) ca[i] = 0.f;
#pragma unroll 4
            for (int ks = 0; ks < 16; ks++) {
                int k0 = ks*16 + h*8;
                short8 af = *(const short8*)(buf + (m*32 + l31)*264 + k0);
                short8 bf = *(const short8*)(fcawB + (size_t)l31*256 + k0);
                ca = __builtin_amdgcn_mfma_f32_32x32x16_bf16(af, bf, ca, 0, 0, 0);
            }
            if (l31 == 0) {
#pragma unroll
                for (int i = 0; i < 16; i++) {
                    int row = (i & 3) + 8*(i >> 2) + 4*h;
                    actL[m*32 + row] = ca[i];           // raw logit
                }
            }
        }
        __syncthreads();   // D: embL/actL ready; h2 reads done
        // ---- P4: relation (K=32 over embL) + exp + redS + pack raw exp into buf
        {
            int nloc = ntR*32 + l31;
            f32x16 ra[2];
#pragma unroll
            for (int mt = 0; mt < 2; mt++)
#pragma unroll
                for (int i = 0; i < 16; i++) ra[mt][i] = 0.f;
#pragma unroll
            for (int s = 0; s < 2; s++) {
                short8 bfrag = *(const short8*)(embL + nloc*40 + s*16 + h*8);
#pragma unroll
                for (int mt = 0; mt < 2; mt++) {
                    int vrow = (vq*2 + mt)*32 + l31;
                    short8 afrag = *(const short8*)(vsb + vrow*32 + s*16 + h*8);
                    ra[mt] = __builtin_amdgcn_mfma_f32_32x32x16_bf16(afrag, bfrag, ra[mt], 0, 0, 0);
                }
            }
            float sm = 0.f;
#pragma unroll
            for (int mt = 0; mt < 2; mt++)
#pragma unroll
                for (int i = 0; i < 16; i++) {
                    float e = __expf(ra[mt][i]);
                    ra[mt][i] = e;
                    sm += e;
                }
            sm += __shfl_xor(sm, 32);
            if (lane < 32) redS[w*32 + l31] = sm;
            // pack UNNORMALIZED exp route (overwrites h2; no reader until E)
#pragma unroll
            for (int mt = 0; mt < 2; mt++) {
#pragma unroll
                for (int g = 0; g < 4; g++) {
                    int vb = (vq*2 + mt)*32 + 8*g + 4*h;
                    unsigned int p0 = pkbf(ra[mt][g*4+0], ra[mt][g*4+1]);
                    unsigned int p1 = pkbf(ra[mt][g*4+2], ra[mt][g*4+3]);
                    *(uint2*)(buf + nloc*264 + vb) = make_uint2(p0, p1);
                }
            }
        }
        __syncthreads();   // E: route, redS ready
        // ---- P5: einsum + deferred (act/sum) scale + nt-store
        {
            f32x16 cc;
#pragma unroll
            for (int i = 0; i < 16; i++) cc[i] = 0.f;
            const unsigned short* rrow = buf + (ntE*32 + l31)*264;
#pragma unroll 4
            for (int ks = 0; ks < 16; ks++) {
                int k0 = ks*16 + h*8;
                short8 bf = *(const short8*)(rrow + k0);
                short8 a0 = *(const short8*)(vcb + arowE + k0);
                cc = __builtin_amdgcn_mfma_f32_32x32x16_bf16(a0, bf, cc, 0, 0, 0);
            }
            int wloc = ntE*32 + l31;
            float smt = 0.f;
#pragma unroll
            for (int q = 0; q < 4; q++) smt += redS[(q*2 + ntE)*32 + l31];
            float al = actL[wloc] + fcab;
            float scale = (1.f / (1.f + __expf(-al))) / smt;
            int ng = n0 + c*64 + wloc;
            if (ng < NWRD) {
                float* ob = out + (size_t)b*128*NWRD + ng;
#pragma unroll
                for (int i = 0; i < 16; i++) {
                    int crow = (i & 3) + 8*(i >> 2) + 4*h;
                    __builtin_nontemporal_store(cc[i]*scale,
                                                ob + (size_t)(cq*32 + crow)*NWRD);
                }
            }
        }
        if (c < 3) __syncthreads();   // F: route reads done -> next fc1 may write buf
    }
}

extern "C" void kernel_launch(void* const* d_in, const int* in_sizes, int n_in,
                              void* d_out, int out_size, void* d_ws, size_t ws_size,
                              hipStream_t stream) {
    const float* view_cell = (const float*)d_in[0];
    const float* v       = (const float*)d_in[1];
    const float* w2c_w1  = (const float*)d_in[2];
    const float* w2c_b1  = (const float*)d_in[3];
    const float* w2c_w2  = (const float*)d_in[4];
    const float* w2c_b2  = (const float*)d_in[5];
    const float* fc1_w   = (const float*)d_in[6];
    const float* fc1_b   = (const float*)d_in[7];
    const float* fc2_w   = (const float*)d_in[8];
    const float* fc2_b   = (const float*)d_in[9];
    const float* fca_w   = (const float*)d_in[10];
    const float* fca_b   = (const float*)d_in[11];
    const float* fce_w   = (const float*)d_in[12];
    const float* fce_b   = (const float*)d_in[13];
    const float* vse_w1  = (const float*)d_in[14];
    const float* vse_b1  = (const float*)d_in[15];
    const float* vse_w2  = (const float*)d_in[16];
    const float* vse_b2  = (const float*)d_in[17];
    float* ws    = (float*)d_ws;
    unsigned short* fc2wT = (unsigned short*)(ws + WS_FC2WT);
    float* wcode = ws + WS_WCODE;
    unsigned short* vsb   = (unsigned short*)(ws + WS_VSB);
    unsigned short* vcb   = (unsigned short*)(ws + WS_VCB);
    unsigned short* fcewT = (unsigned short*)(ws + WS_FCEWT);
    unsigned short* fcawB = (unsigned short*)(ws + WS_FCAWB);
    float* out   = (float*)d_out;

    kprep<<<PREP_N, 256, 0, stream>>>(view_cell, vcb,
                                      w2c_w2, v, w2c_w1, w2c_b1, w2c_b2, wcode,
                                      vse_w1, vse_b1, vse_w2, vse_b2, vsb,
                                      fc2_w, fc2wT, fce_w, fcewT, fca_w, fcawB);
    (void)hipFuncSetAttribute((const void*)k45,
                              hipFuncAttributeMaxDynamicSharedMemorySize, K45_LDS);
    dim3 g45(8, 64);
    k45<<<g45, 512, K45_LDS, stream>>>(vcb, wcode, fc1_w, fc1_b, fc2wT, fc2_b,
                                       fca_b, fcawB, fcewT, fce_b, vsb, out);
}

// Round 5
// 233.394 us; speedup vs baseline: 1.5175x; 1.0764x over previous
//
#include <hip/hip_runtime.h>
#include <hip/hip_bf16.h>
#include <math.h>

#define NWRD 2000

typedef __attribute__((ext_vector_type(8)))  short short8;   // 8 bf16 (4 VGPRs)
typedef __attribute__((ext_vector_type(16))) float f32x16;   // MFMA 32x32 acc

// workspace layout (float offsets)
#define WS_FC2WT 0                         // 256*256 bf16
#define WS_WCODE (WS_FC2WT + 32768)        // 64*6000 f32  ([b][n*3+c])
#define WS_VSB   (WS_WCODE + 384000)       // 256*32 bf16
#define WS_W2T   (WS_VSB + 4096)           // (unused)
#define WS_VCB   (WS_W2T + 1536000)        // 64*128*256 bf16
#define WS_FCEWT (WS_VCB + 1048576)        // 32*256 bf16
#define WS_H0B   (WS_FCEWT + 4096)         // (unused)
#define WS_FCAWB (WS_H0B + 16384)          // 32*256 bf16 (row0=fca_w, rest 0)

__device__ __forceinline__ unsigned short f2bf(float x) {
    unsigned int u = __float_as_uint(x);
    u += 0x7fffu + ((u >> 16) & 1u);       // round-to-nearest-even
    return (unsigned short)(u >> 16);
}
// hardware packed f32->bf16 (RNE), 1 instr per 2 values
__device__ __forceinline__ unsigned int pkbf(float lo, float hi) {
    unsigned int r;
    asm("v_cvt_pk_bf16_f32 %0, %1, %2" : "=v"(r) : "v"(lo), "v"(hi));
    return r;
}

// ================ KPREP: prep jobs + fused wcode GEMM in ONE launch ================
// [0,94): wcode GEMM | [94,1118): vcb | [1118,1150): vsb | [1150,1166): fc2wT | 1166: fcewT+fcawB
#define PR_K2  94
#define PR_VCB (PR_K2 + 1024)
#define PR_VSB (PR_VCB + 32)
#define PR_FC2 (PR_VSB + 16)
#define PREP_N (PR_FC2 + 1)
__global__ __launch_bounds__(256) void kprep(
        const float* __restrict__ vc, unsigned short* __restrict__ vcb,
        const float* __restrict__ w2,
        const float* __restrict__ v, const float* __restrict__ w1,
        const float* __restrict__ b1, const float* __restrict__ b2,
        float* __restrict__ wcode,
        const float* __restrict__ vse_w1, const float* __restrict__ vse_b1,
        const float* __restrict__ vse_w2, const float* __restrict__ vse_b2,
        unsigned short* __restrict__ vsb,
        const float* __restrict__ fc2_w, unsigned short* __restrict__ fc2wT,
        const float* __restrict__ fce_w, unsigned short* __restrict__ fcewT,
        const float* __restrict__ fca_w, unsigned short* __restrict__ fcawB) {
    __shared__ __align__(16) unsigned short smem[10240];   // 20.5 KB unioned scratch
    int bid = blockIdx.x, t = threadIdx.x;
    if (bid < PR_K2) {
        // ---- wcode[64 b][64 n] = relu(v@w1+b1) @ w2[:,slice] + b2, via MFMA
        unsigned short* ha = smem;            // [64][72]
        unsigned short* wb = smem + 4608;     // [64][72]
        int n0 = bid * 64;
        int w = t >> 6, lane = t & 63, l31 = lane & 31, h = lane >> 5;
        int mt = w & 1, nt = w >> 1;
        int kk = t & 63, mg = t >> 6;
        int colc = n0 + kk; if (colc > 5999) colc = 5999;
        f32x16 acc;
#pragma unroll
        for (int i = 0; i < 16; i++) acc[i] = 0.f;
        for (int p = 0; p < 8; p++) {
            int k0 = p * 64;
            // h0 panel: thread owns column kk, 16 rows (m = b index); w1 reads coalesced
            float w1c[7];
#pragma unroll
            for (int q = 0; q < 7; q++) w1c[q] = w1[q*512 + k0 + kk];
            float bbv = b1[k0 + kk];
#pragma unroll
            for (int mm = 0; mm < 16; mm++) {
                int m = mg*16 + mm;           // wave-uniform m -> scalar v loads
                float s = bbv;
#pragma unroll
                for (int q = 0; q < 7; q++) s = fmaf(v[m*7 + q], w1c[q], s);
                ha[m*72 + kk] = f2bf(fmaxf(s, 0.f));
            }
            // w2 panel transpose: coalesced f32 row reads -> bf16 n-major LDS
#pragma unroll
            for (int i = 0; i < 16; i++)
                wb[kk*72 + mg*16 + i] = f2bf(w2[(size_t)(k0 + mg*16 + i)*6000 + colc]);
            __syncthreads();
#pragma unroll
            for (int ks = 0; ks < 4; ks++) {
                short8 af = *(const short8*)(ha + (mt*32 + l31)*72 + ks*16 + h*8);
                short8 bf = *(const short8*)(wb + (nt*32 + l31)*72 + ks*16 + h*8);
                acc = __builtin_amdgcn_mfma_f32_32x32x16_bf16(af, bf, acc, 0, 0, 0);
            }
            __syncthreads();
        }
        int n = n0 + nt*32 + l31;
        if (n < 6000) {
            float bias = b2[n];
#pragma unroll
            for (int i = 0; i < 16; i++) {
                int row = (i & 3) + 8*(i >> 2) + 4*h;
                wcode[(size_t)(mt*32 + row)*6000 + n] = acc[i] + bias;
            }
        }
    } else if (bid < PR_VCB) {
        // ---- view_cell f32 -> bf16
        int i = ((bid - PR_K2) * 256 + t) * 8;
        float4 f0 = *(const float4*)(vc + i);
        float4 f1 = *(const float4*)(vc + i + 4);
        union { short8 v8; unsigned int u[4]; } o;
        o.u[0] = pkbf(f0.x, f0.y); o.u[1] = pkbf(f0.z, f0.w);
        o.u[2] = pkbf(f1.x, f1.y); o.u[3] = pkbf(f1.z, f1.w);
        *(short8*)(vcb + i) = o.v8;
    } else if (bid < PR_VSB) {
        // ---- vs MLP -> bf16
        float* hs = (float*)smem;   // [8][128]
        int blk = bid - PR_VCB;
        int m = t & 127, half = t >> 7;
#pragma unroll
        for (int q = 0; q < 4; q++) {
            int vloc = half*4 + q;
            int vv = blk*8 + vloc;
            float x = (2.f/15.f)*(float)(vv >> 4) - 1.f;
            float y = (2.f/15.f)*(float)(vv & 15) - 1.f;
            float hh = vse_b1[m] + x*vse_w1[m] + y*vse_w1[128 + m];
            hs[vloc*128 + m] = fmaxf(hh, 0.f);
        }
        __syncthreads();
        int vloc = t >> 5, e = t & 31;
        float s = vse_b2[e];
        for (int mm = 0; mm < 128; mm++) s = fmaf(hs[vloc*128 + mm], vse_w2[mm*32 + e], s);
        vsb[(blk*8 + vloc)*32 + e] = f2bf(s);
    } else if (bid < PR_FC2) {
        // ---- fc2_w -> fc2wT (n-major bf16)
        unsigned short (*tile)[72] = (unsigned short(*)[72])smem;
        int b2t = bid - PR_VSB;
        int k0t = (b2t >> 2) * 64, n0t = (b2t & 3) * 64;
        int nl = t & 63, kb = (t >> 6) * 16;
#pragma unroll
        for (int i = 0; i < 16; i++)
            tile[kb + i][nl] = f2bf(fc2_w[(size_t)(k0t + kb + i)*256 + n0t + nl]);
        __syncthreads();
        int kl = t & 63, nb = (t >> 6) * 16;
#pragma unroll
        for (int i = 0; i < 16; i++)
            fc2wT[(size_t)(n0t + nb + i)*256 + k0t + kl] = tile[kl][nb + i];
    } else {
        // ---- fcewT (32x256 bf16, e-major) + fcawB (row0 = fca_w, rest 0)
        int e = t & 31, kb = (t >> 5) * 32;
        unsigned short tmp[32];
#pragma unroll
        for (int i = 0; i < 32; i++) tmp[i] = f2bf(fce_w[(size_t)(kb + i)*32 + e]);
#pragma unroll
        for (int i = 0; i < 4; i++)
            *(short8*)(fcewT + (size_t)e*256 + kb + i*8) = *(short8*)(tmp + i*8);
#pragma unroll
        for (int i = 0; i < 32; i++)
            fcawB[(size_t)e*256 + kb + i] = (e == 0) ? f2bf(fca_w[kb + i]) : (unsigned short)0;
    }
}

// ================ K45: single-buffer in-place pipeline, 3 blocks/CU ================
// grid (8 nblk, 64 b), 512 threads (8 waves), 4 chunks of 64 words.
// ONE [64][264] bf16 buffer holds h1 -> (in-place) h2 -> (in-place) exp-route.
// fc2 reads h1 fully into accumulators, barrier, writes h2 over it.
// Deferred softmax: route stores raw exp; act/sum applied in einsum epilogue.
// LDS: buf @0 (33792) | embL [64][40] @33792 | wcs[768] @38912 | redS[8][32] @41984 |
//      actL[64] @43008. total 43264 B -> 3 blocks/CU (24 waves).
// NOTE launch_bounds min-waves/EU MUST stay <=4: at 6 the VGPR cap (85) spills
// the f32x16 accumulators to scratch (round-4: VGPR=40, FETCH+WRITE +88 MB, 143us).
#define K45_LDS 43264
__device__ __forceinline__ void fc1_row(const float* __restrict__ wr,
        const float4& wa, const float4& wb4, const float4& wc, const float4& bb4,
        unsigned short* dst) {
    float c0 = wr[0], c1 = wr[1], c2 = wr[2];
    float v0 = fmaxf(fmaf(c2, wc.x, fmaf(c1, wb4.x, fmaf(c0, wa.x, bb4.x))), 0.f);
    float v1 = fmaxf(fmaf(c2, wc.y, fmaf(c1, wb4.y, fmaf(c0, wa.y, bb4.y))), 0.f);
    float v2 = fmaxf(fmaf(c2, wc.z, fmaf(c1, wb4.z, fmaf(c0, wa.z, bb4.z))), 0.f);
    float v3 = fmaxf(fmaf(c2, wc.w, fmaf(c1, wb4.w, fmaf(c0, wa.w, bb4.w))), 0.f);
    uint2 p;
    p.x = pkbf(v0, v1);
    p.y = pkbf(v2, v3);
    *(uint2*)dst = p;
}
__global__ __launch_bounds__(512, 4) void k45(
        const unsigned short* __restrict__ vcb,
        const float* __restrict__ wcode,
        const float* __restrict__ fc1_w, const float* __restrict__ fc1_b,
        const unsigned short* __restrict__ fc2wT, const float* __restrict__ fc2_b,
        const float* __restrict__ fca_b_p,
        const unsigned short* __restrict__ fcawB,
        const unsigned short* __restrict__ fcewT, const float* __restrict__ fce_b,
        const unsigned short* __restrict__ vsb,
        float* __restrict__ out) {
    extern __shared__ char lds[];
    unsigned short* buf   = (unsigned short*)lds;             // [64][264]
    unsigned short* embL  = (unsigned short*)(lds + 33792);   // [64][40]
    float* wcsAll = (float*)(lds + 38912);                    // [768]
    float* redS   = (float*)(lds + 41984);                    // [8][32]
    float* actL   = (float*)(lds + 43008);                    // [64] raw fca logits
    int t = threadIdx.x;
    int w = t >> 6, lane = t & 63, l31 = lane & 31, h = lane >> 5;
    int b = blockIdx.y;
    int n0 = blockIdx.x * 256;

    // ---- stage all 4 chunks' wcode once (768 f32)
    {
        const float* wsrc = wcode + (size_t)b*6000;
        int i0 = n0*3 + t;
        wcsAll[t] = wsrc[i0 < 6000 ? i0 : 5999];
        if (t < 256) {
            int i1 = n0*3 + 512 + t;
            wcsAll[512 + t] = wsrc[i1 < 6000 ? i1 : 5999];
        }
    }
    // hoisted invariants (small live set; fc1 weights reloaded per chunk)
    int jq = (t & 63) * 4;
    int mtF = w & 1, nqF = w >> 1;             // fc2: wave = (m-half, n-quarter)
    int colA = nqF*64 + l31, colB = colA + 32;
    float baA = fc2_b[colA], baB = fc2_b[colB];
    float be = fce_b[l31];
    float fcab = fca_b_p[0];
    int ntR = w & 1, vq = w >> 1;              // relation tiling
    int cq = w >> 1, ntE = w & 1;              // einsum tiling
    size_t arowE = ((size_t)(b*128 + cq*32 + l31))*256;
    __syncthreads();

    for (int c = 0; c < 4; c++) {
        // ---- P0: fc1 -> buf (h1)
        {
            float4 wa  = *(const float4*)(fc1_w + jq);
            float4 wb4 = *(const float4*)(fc1_w + 256 + jq);
            float4 wc  = *(const float4*)(fc1_w + 512 + jq);
            float4 bb4 = *(const float4*)(fc1_b + jq);
#pragma unroll
            for (int rr = 0; rr < 8; rr++) {
                int r = w*8 + rr;
                fc1_row(wcsAll + (c*64 + r)*3, wa, wb4, wc, bb4, buf + r*264 + jq);
            }
        }
        __syncthreads();   // A: h1 ready
        // ---- P1: fc2 MFMA (read-only; wave reads only its m-half of A)
        f32x16 c0, c1;
#pragma unroll
        for (int i = 0; i < 16; i++) { c0[i] = 0.f; c1[i] = 0.f; }
#pragma unroll 4
        for (int ks = 0; ks < 16; ks++) {
            int k0 = ks*16 + h*8;
            short8 af  = *(const short8*)(buf + (mtF*32 + l31)*264 + k0);
            short8 bf0 = *(const short8*)(fc2wT + (size_t)colA*256 + k0);
            short8 bf1 = *(const short8*)(fc2wT + (size_t)colB*256 + k0);
            c0 = __builtin_amdgcn_mfma_f32_32x32x16_bf16(af, bf0, c0, 0, 0, 0);
            c1 = __builtin_amdgcn_mfma_f32_32x32x16_bf16(af, bf1, c1, 0, 0, 0);
        }
        __syncthreads();   // B: all h1 reads done
        // ---- P2: write h2 in place
#pragma unroll
        for (int i = 0; i < 16; i++) {
            int row = (i & 3) + 8*(i >> 2) + 4*h;
            unsigned int pk = pkbf(fmaxf(c0[i] + baA, 0.f), fmaxf(c1[i] + baB, 0.f));
            buf[(mtF*32 + row)*264 + colA] = (unsigned short)pk;
            buf[(mtF*32 + row)*264 + colB] = (unsigned short)(pk >> 16);
        }
        __syncthreads();   // C: h2 ready
        // ---- P3: fce (waves 0-1) + fca (waves 2-3) read h2
        if (w < 2) {
            f32x16 ce;
#pragma unroll
            for (int i = 0; i < 16; i++) ce[i] = 0.f;
#pragma unroll 4
            for (int ks = 0; ks < 16; ks++) {
                int k0 = ks*16 + h*8;
                short8 af = *(const short8*)(buf + (w*32 + l31)*264 + k0);
                short8 bf = *(const short8*)(fcewT + (size_t)l31*256 + k0);
                ce = __builtin_amdgcn_mfma_f32_32x32x16_bf16(af, bf, ce, 0, 0, 0);
            }
#pragma unroll
            for (int i = 0; i < 16; i += 2) {
                int row = (i & 3) + 8*(i >> 2) + 4*h;
                unsigned int pk = pkbf(ce[i] + be, ce[i+1] + be);
                embL[(w*32 + row)*40 + l31]     = (unsigned short)pk;
                embL[(w*32 + row + 1)*40 + l31] = (unsigned short)(pk >> 16);
            }
        } else if (w < 4) {
            int m = w - 2;
            f32x16 ca;
#pragma unroll
            for (int i = 0; i < 16; i++) ca[i] = 0.f;
#pragma unroll 4
            for (int ks = 0; ks < 16; ks++) {
                int k0 = ks*16 + h*8;
                short8 af = *(const short8*)(buf + (m*32 + l31)*264 + k0);
                short8 bf = *(const short8*)(fcawB + (size_t)l31*256 + k0);
                ca = __builtin_amdgcn_mfma_f32_32x32x16_bf16(af, bf, ca, 0, 0, 0);
            }
            if (l31 == 0) {
#pragma unroll
                for (int i = 0; i < 16; i++) {
                    int row = (i & 3) + 8*(i >> 2) + 4*h;
                    actL[m*32 + row] = ca[i];           // raw logit
                }
            }
        }
        __syncthreads();   // D: embL/actL ready; h2 reads done
        // ---- P4: relation (K=32 over embL) + exp + redS + pack raw exp into buf
        {
            int nloc = ntR*32 + l31;
            f32x16 ra[2];
#pragma unroll
            for (int mt = 0; mt < 2; mt++)
#pragma unroll
                for (int i = 0; i < 16; i++) ra[mt][i] = 0.f;
#pragma unroll
            for (int s = 0; s < 2; s++) {
                short8 bfrag = *(const short8*)(embL + nloc*40 + s*16 + h*8);
#pragma unroll
                for (int mt = 0; mt < 2; mt++) {
                    int vrow = (vq*2 + mt)*32 + l31;
                    short8 afrag = *(const short8*)(vsb + vrow*32 + s*16 + h*8);
                    ra[mt] = __builtin_amdgcn_mfma_f32_32x32x16_bf16(afrag, bfrag, ra[mt], 0, 0, 0);
                }
            }
            float sm = 0.f;
#pragma unroll
            for (int mt = 0; mt < 2; mt++)
#pragma unroll
                for (int i = 0; i < 16; i++) {
                    float e = __expf(ra[mt][i]);
                    ra[mt][i] = e;
                    sm += e;
                }
            sm += __shfl_xor(sm, 32);
            if (lane < 32) redS[w*32 + l31] = sm;
            // pack UNNORMALIZED exp route (overwrites h2; no reader until E)
#pragma unroll
            for (int mt = 0; mt < 2; mt++) {
#pragma unroll
                for (int g = 0; g < 4; g++) {
                    int vb = (vq*2 + mt)*32 + 8*g + 4*h;
                    unsigned int p0 = pkbf(ra[mt][g*4+0], ra[mt][g*4+1]);
                    unsigned int p1 = pkbf(ra[mt][g*4+2], ra[mt][g*4+3]);
                    *(uint2*)(buf + nloc*264 + vb) = make_uint2(p0, p1);
                }
            }
        }
        __syncthreads();   // E: route, redS ready
        // ---- P5: einsum + deferred (act/sum) scale + nt-store
        {
            f32x16 cc;
#pragma unroll
            for (int i = 0; i < 16; i++) cc[i] = 0.f;
            const unsigned short* rrow = buf + (ntE*32 + l31)*264;
#pragma unroll 4
            for (int ks = 0; ks < 16; ks++) {
                int k0 = ks*16 + h*8;
                short8 bf = *(const short8*)(rrow + k0);
                short8 a0 = *(const short8*)(vcb + arowE + k0);
                cc = __builtin_amdgcn_mfma_f32_32x32x16_bf16(a0, bf, cc, 0, 0, 0);
            }
            int wloc = ntE*32 + l31;
            float smt = 0.f;
#pragma unroll
            for (int q = 0; q < 4; q++) smt += redS[(q*2 + ntE)*32 + l31];
            float al = actL[wloc] + fcab;
            float scale = (1.f / (1.f + __expf(-al))) / smt;
            int ng = n0 + c*64 + wloc;
            if (ng < NWRD) {
                float* ob = out + (size_t)b*128*NWRD + ng;
#pragma unroll
                for (int i = 0; i < 16; i++) {
                    int crow = (i & 3) + 8*(i >> 2) + 4*h;
                    __builtin_nontemporal_store(cc[i]*scale,
                                                ob + (size_t)(cq*32 + crow)*NWRD);
                }
            }
        }
        if (c < 3) __syncthreads();   // F: route reads done -> next fc1 may write buf
    }
}

extern "C" void kernel_launch(void* const* d_in, const int* in_sizes, int n_in,
                              void* d_out, int out_size, void* d_ws, size_t ws_size,
                              hipStream_t stream) {
    const float* view_cell = (const float*)d_in[0];
    const float* v       = (const float*)d_in[1];
    const float* w2c_w1  = (const float*)d_in[2];
    const float* w2c_b1  = (const float*)d_in[3];
    const float* w2c_w2  = (const float*)d_in[4];
    const float* w2c_b2  = (const float*)d_in[5];
    const float* fc1_w   = (const float*)d_in[6];
    const float* fc1_b   = (const float*)d_in[7];
    const float* fc2_w   = (const float*)d_in[8];
    const float* fc2_b   = (const float*)d_in[9];
    const float* fca_w   = (const float*)d_in[10];
    const float* fca_b   = (const float*)d_in[11];
    const float* fce_w   = (const float*)d_in[12];
    const float* fce_b   = (const float*)d_in[13];
    const float* vse_w1  = (const float*)d_in[14];
    const float* vse_b1  = (const float*)d_in[15];
    const float* vse_w2  = (const float*)d_in[16];
    const float* vse_b2  = (const float*)d_in[17];
    float* ws    = (float*)d_ws;
    unsigned short* fc2wT = (unsigned short*)(ws + WS_FC2WT);
    float* wcode = ws + WS_WCODE;
    unsigned short* vsb   = (unsigned short*)(ws + WS_VSB);
    unsigned short* vcb   = (unsigned short*)(ws + WS_VCB);
    unsigned short* fcewT = (unsigned short*)(ws + WS_FCEWT);
    unsigned short* fcawB = (unsigned short*)(ws + WS_FCAWB);
    float* out   = (float*)d_out;

    kprep<<<PREP_N, 256, 0, stream>>>(view_cell, vcb,
                                      w2c_w2, v, w2c_w1, w2c_b1, w2c_b2, wcode,
                                      vse_w1, vse_b1, vse_w2, vse_b2, vsb,
                                      fc2_w, fc2wT, fce_w, fcewT, fca_w, fcawB);
    (void)hipFuncSetAttribute((const void*)k45,
                              hipFuncAttributeMaxDynamicSharedMemorySize, K45_LDS);
    dim3 g45(8, 64);
    k45<<<g45, 512, K45_LDS, stream>>>(vcb, wcode, fc1_w, fc1_b, fc2wT, fc2_b,
                                       fca_b, fcawB, fcewT, fce_b, vsb, out);
}